// Round 8
// baseline (1016.161 us; speedup 1.0000x reference)
//
#include <hip/hip_runtime.h>
#include <math.h>

#define NB    512   // blocks, 2 batch rows each -> 2 blocks/CU
#define NT    512   // 8 waves: 0-3 = layer0 (X), 4-7 = layer1 (Y)
#define ROWS  2
#define B_TOT 1024
#define T_TOT 512
#define HROW  104   // f16 per h-row (208 B; 16B-aligned)
#define XT    32

typedef _Float16 f16;
typedef _Float16 f16x8 __attribute__((ext_vector_type(8)));
typedef float    f32x4 __attribute__((ext_vector_type(4)));

__device__ __forceinline__ float rcp_f(float v){ return __builtin_amdgcn_rcpf(v); }
__device__ __forceinline__ float sig_f(float x){ return rcp_f(1.0f + __expf(-x)); }
__device__ __forceinline__ float tanh_f(float x){ return 1.0f - 2.0f*rcp_f(__expf(2.0f*x) + 1.0f); }

#define MFMA16(a,b,c) __builtin_amdgcn_mfma_f32_16x16x32_f16((a),(b),(c),0,0,0)

__global__ __launch_bounds__(NT, 4) void lstm_pipe(
    const float* __restrict__ x,
    const float* __restrict__ h0i, const float* __restrict__ c0i,
    const float* __restrict__ wih0, const float* __restrict__ whh0,
    const float* __restrict__ bih0, const float* __restrict__ bhh0,
    const float* __restrict__ wih1, const float* __restrict__ whh1,
    const float* __restrict__ bih1, const float* __restrict__ bhh1,
    const float* __restrict__ wmean, const float* __restrict__ bmean,
    const float* __restrict__ wcrit, const float* __restrict__ bcrit,
    float* __restrict__ out)
{
    const int tid  = threadIdx.x;
    const int lane = tid & 63;
    const int wv   = tid >> 6;
    const bool isX = (wv < 4);        // layer-0 waves
    const int ug   = wv & 3;          // unit-group: units [16ug,16ug+16)
    const int l15  = lane & 15;       // A-row m / B-col n (batch)
    const int kgrp = lane >> 4;       // k-group
    const int r0   = blockIdx.x * ROWS;
    // packed cell-update ownership: lanes 0..31 own one (unit,batch) slot each
    const bool act  = (lane < 32);
    const int  uloc = (lane >> 1) & 15;  // unit-local 0..15
    const int  bb   = lane & 1;          // batch row 0..1

    // h0 rows: k0..63 = h0, k64..68 = x[t], rest 0
    __shared__ __align__(16) f16 hbuf[2][16][HROW];
    // h1 rows: k0..63 = h1, rest 0
    __shared__ __align__(16) f16 ybuf[2][16][HROW];
    __shared__ float xt[ROWS][XT][5];
    // wave-private gate bounce buffer: [wave][gate][batch][unit-local]
    __shared__ __align__(16) float gbuf[8][4][ROWS][16];

    // ---------- per-wave constant fragments ----------
    f16x8 aX[4][3];   // X: whh0 chunks 0,1 + (x|0) chunk 2
    f16x8 aY[4][4];   // Y: wih1 chunks 0,1 ; whh1 chunks 2,3
    float bpk[4];     // bias for this lane's owned unit, per gate
    float cOwn;       // owned cell state

    if (isX){
#pragma unroll
        for (int q = 0; q < 4; ++q){
            const int gr = q*64 + ug*16 + l15;
#pragma unroll
            for (int c2 = 0; c2 < 2; ++c2){
                const float* pw = whh0 + (size_t)gr*64 + c2*32 + kgrp*8;
                f16x8 v;
#pragma unroll
                for (int j = 0; j < 8; ++j) v[j] = (f16)pw[j];
                aX[q][c2] = v;
            }
            {   // chunk 2: global k 64..95 -> x rows 64..68, rest 0
                f16x8 v;
#pragma unroll
                for (int j = 0; j < 8; ++j){
                    int k = kgrp*8 + j;
                    v[j] = (k < 5) ? (f16)wih0[gr*5 + k] : (f16)0.f;
                }
                aX[q][2] = v;
            }
            const int gu = q*64 + ug*16 + uloc;
            bpk[q] = bih0[gu] + bhh0[gu];
        }
        cOwn = c0i[(size_t)(r0+bb)*64 + ug*16 + uloc];
    } else {
#pragma unroll
        for (int q = 0; q < 4; ++q){
            const int gr = q*64 + ug*16 + l15;
#pragma unroll
            for (int c2 = 0; c2 < 2; ++c2){
                const float* pw = wih1 + (size_t)gr*64 + c2*32 + kgrp*8;
                const float* qw = whh1 + (size_t)gr*64 + c2*32 + kgrp*8;
                f16x8 v, u2;
#pragma unroll
                for (int j = 0; j < 8; ++j){ v[j] = (f16)pw[j]; u2[j] = (f16)qw[j]; }
                aY[q][c2]   = v;
                aY[q][2+c2] = u2;
            }
            const int gu = q*64 + ug*16 + uloc;
            bpk[q] = bih1[gu] + bhh1[gu];
        }
        cOwn = c0i[(size_t)B_TOT*64 + (size_t)(r0+bb)*64 + ug*16 + uloc];
    }

    // ---------- LDS init ----------
    for (int e = tid; e < 2*16*HROW; e += NT){
        ((f16*)hbuf)[e] = (f16)0.f;
        ((f16*)ybuf)[e] = (f16)0.f;
    }
    __syncthreads();
    if (tid < ROWS*64){
        int cc = tid >> 6, u = tid & 63;
        hbuf[0][cc][u] = (f16)h0i[(size_t)(r0+cc)*64 + u];
        ybuf[1][cc][u] = (f16)h0i[(size_t)B_TOT*64 + (size_t)(r0+cc)*64 + u];
    }
    if (tid < ROWS*5){
        int cc = tid/5, i = tid - cc*5;
        hbuf[0][cc][64+i] = (f16)x[(size_t)(r0+cc)*T_TOT*5 + i];  // x[0]
    }
    for (int e = tid; e < ROWS*XT*5; e += NT){
        int r = e/(XT*5), rem = e - r*(XT*5), ts = rem/5, i = rem - ts*5;
        xt[r][ts][i] = x[((size_t)(r0+r)*T_TOT + ts)*5 + i];      // tile 0
    }
    __syncthreads();

    // ---------- 513 pipelined ticks: X = layer0 step t, Y = layer1 step t-1 ----------
#pragma unroll 1
    for (int t = 0; t <= T_TOT; ++t){
        const int p = t & 1;

        if ((t+1) < T_TOT && ((t+1) & 31) == 0){      // stage next x tile
            for (int e = tid; e < ROWS*XT*5; e += NT){
                int r = e/(XT*5), rem = e - r*(XT*5), ts = rem/5, i = rem - ts*5;
                xt[r][ts][i] = x[((size_t)(r0+r)*T_TOT + (t+1+ts))*5 + i];
            }
            __syncthreads();
        }
        if ((t+1) < T_TOT && tid < ROWS*5){           // x[t+1] -> write buffer
            int cc = tid/5, i = tid - cc*5;
            hbuf[p^1][cc][64+i] = (f16)xt[cc][(t+1)&31][i];
        }

        if (isX){ if (t < T_TOT){
            const f16* bp = &hbuf[p][l15][kgrp*8];
            f16x8 b0 = *(const f16x8*)(bp);
            f16x8 b1 = *(const f16x8*)(bp + 32);
            f16x8 b2 = *(const f16x8*)(bp + 64);
#pragma unroll
            for (int q = 0; q < 4; ++q){
                f32x4 a = {0.f,0.f,0.f,0.f};
                a = MFMA16(aX[q][0], b0, a);
                a = MFMA16(aX[q][1], b1, a);
                a = MFMA16(aX[q][2], b2, a);
                if (l15 < ROWS) *(f32x4*)&gbuf[wv][q][l15][kgrp*4] = a;
            }
            if (act){
                float ii = gbuf[wv][0][bb][uloc] + bpk[0];
                float ff = gbuf[wv][1][bb][uloc] + bpk[1];
                float gg = gbuf[wv][2][bb][uloc] + bpk[2];
                float oo = gbuf[wv][3][bb][uloc] + bpk[3];
                cOwn = sig_f(ff)*cOwn + sig_f(ii)*tanh_f(gg);
                hbuf[p^1][bb][ug*16 + uloc] = (f16)(sig_f(oo)*tanh_f(cOwn));
            }
        }} else { if (t >= 1){
            const f16* hp = &hbuf[p][l15][kgrp*8];
            f16x8 b0 = *(const f16x8*)(hp);
            f16x8 b1 = *(const f16x8*)(hp + 32);
            const f16* yp = &ybuf[p][l15][kgrp*8];
            f16x8 b2 = *(const f16x8*)(yp);
            f16x8 b3 = *(const f16x8*)(yp + 32);
#pragma unroll
            for (int q = 0; q < 4; ++q){
                f32x4 a = {0.f,0.f,0.f,0.f};
                a = MFMA16(aY[q][0], b0, a);
                a = MFMA16(aY[q][1], b1, a);
                a = MFMA16(aY[q][2], b2, a);
                a = MFMA16(aY[q][3], b3, a);
                if (l15 < ROWS) *(f32x4*)&gbuf[wv][q][l15][kgrp*4] = a;
            }
            if (act){
                float ii = gbuf[wv][0][bb][uloc] + bpk[0];
                float ff = gbuf[wv][1][bb][uloc] + bpk[1];
                float gg = gbuf[wv][2][bb][uloc] + bpk[2];
                float oo = gbuf[wv][3][bb][uloc] + bpk[3];
                cOwn = sig_f(ff)*cOwn + sig_f(ii)*tanh_f(gg);
                ybuf[p^1][bb][ug*16 + uloc] = (f16)(sig_f(oo)*tanh_f(cOwn));
            }
        }}
        __syncthreads();
    }

    // ---------- heads: final h1 = ybuf[1] (written at tick 512) ----------
    if (wv < ROWS){
        const int cc = wv, u = lane;
        float hr = (float)ybuf[1][cc][u];
        float pm = hr * wmean[u];
        float pc = hr * wcrit[u];
#pragma unroll
        for (int o = 32; o > 0; o >>= 1){
            pm += __shfl_down(pm, o);
            pc += __shfl_down(pc, o);
        }
        if (u == 0){
            float m = pm + bmean[0];
            out[r0+cc]           = 2.f*tanh_f(m);
            out[B_TOT + r0+cc]   = __logf(1.f + __expf(m));
            out[2*B_TOT + r0+cc] = pc + bcrit[0];
        }
    }
}

extern "C" void kernel_launch(void* const* d_in, const int* in_sizes, int n_in,
                              void* d_out, int out_size, void* d_ws, size_t ws_size,
                              hipStream_t stream) {
    const float* x     = (const float*)d_in[0];
    const float* h0i   = (const float*)d_in[1];
    const float* c0i   = (const float*)d_in[2];
    const float* wih0  = (const float*)d_in[3];
    const float* whh0  = (const float*)d_in[4];
    const float* bih0  = (const float*)d_in[5];
    const float* bhh0  = (const float*)d_in[6];
    const float* wih1  = (const float*)d_in[7];
    const float* whh1  = (const float*)d_in[8];
    const float* bih1  = (const float*)d_in[9];
    const float* bhh1  = (const float*)d_in[10];
    const float* wmean = (const float*)d_in[11];
    const float* bmean = (const float*)d_in[12];
    const float* wcrit = (const float*)d_in[13];
    const float* bcrit = (const float*)d_in[14];

    lstm_pipe<<<NB, NT, 0, stream>>>(x, h0i, c0i, wih0, whh0, bih0, bhh0,
                                     wih1, whh1, bih1, bhh1,
                                     wmean, bmean, wcrit, bcrit,
                                     (float*)d_out);
}

// Round 9
// 491.847 us; speedup vs baseline: 2.0660x; 2.0660x over previous
//
#include <hip/hip_runtime.h>
#include <math.h>

#define NB    512   // blocks, 2 batch rows each -> 2 blocks/CU
#define NT    512   // 8 waves: 0-3 = layer0 (X), 4-7 = layer1 (Y)
#define ROWS  2
#define B_TOT 1024
#define T_TOT 512
#define HROW  104   // f16 per h-row (208 B; 16B-aligned)
#define XT    32

typedef _Float16 f16;
typedef _Float16 f16x8 __attribute__((ext_vector_type(8)));
typedef float    f32x4 __attribute__((ext_vector_type(4)));

__device__ __forceinline__ float rcp_f(float v){ return __builtin_amdgcn_rcpf(v); }
__device__ __forceinline__ float sig_f(float x){ return rcp_f(1.0f + __expf(-x)); }
__device__ __forceinline__ float tanh_f(float x){ return 1.0f - 2.0f*rcp_f(__expf(2.0f*x) + 1.0f); }

#define MFMA16(a,b,c) __builtin_amdgcn_mfma_f32_16x16x32_f16((a),(b),(c),0,0,0)

__global__ __launch_bounds__(NT, 4) void lstm_pipe(
    const float* __restrict__ x,
    const float* __restrict__ h0i, const float* __restrict__ c0i,
    const float* __restrict__ wih0, const float* __restrict__ whh0,
    const float* __restrict__ bih0, const float* __restrict__ bhh0,
    const float* __restrict__ wih1, const float* __restrict__ whh1,
    const float* __restrict__ bih1, const float* __restrict__ bhh1,
    const float* __restrict__ wmean, const float* __restrict__ bmean,
    const float* __restrict__ wcrit, const float* __restrict__ bcrit,
    float* __restrict__ out)
{
    const int tid  = threadIdx.x;
    const int lane = tid & 63;
    const int wv   = tid >> 6;
    const bool isX = (wv < 4);        // layer-0 waves
    const int ug   = wv & 3;          // unit-group: units [16ug,16ug+16)
    const int l15  = lane & 15;       // A-row m / B-col n (batch)
    const int kgrp = lane >> 4;       // k-group
    const int r0   = blockIdx.x * ROWS;
    // packed cell-update ownership: lanes 0..31 own one (unit,batch) slot each
    const bool act  = (lane < 32);
    const int  uloc = (lane >> 1) & 15;  // unit-local 0..15
    const int  bb   = lane & 1;          // batch row 0..1

    // h0 rows: k0..63 = h0, k64..68 = x[t], rest 0
    __shared__ __align__(16) f16 hbuf[2][16][HROW];
    // h1 rows: k0..63 = h1, rest 0
    __shared__ __align__(16) f16 ybuf[2][16][HROW];
    __shared__ float xt[ROWS][XT][5];
    // wave-private gate bounce buffer: [wave][gate][batch][unit-local]
    __shared__ __align__(16) float gbuf[8][4][ROWS][16];

    // ---------- per-wave constant fragments (SINGLE array: X and Y share it;
    // isX is wave-uniform, so each wave loads exactly one weight set.
    // Union register demand 64 VGPRs, not 112 -> fits the 4-waves/SIMD cap
    // without scratch spill (R8's failure mode). ----------
    f16x8 afr[4][4];
    float bpk[4];     // bias for this lane's owned unit, per gate
    float cOwn;       // owned cell state

    if (isX){
#pragma unroll
        for (int q = 0; q < 4; ++q){
            const int gr = q*64 + ug*16 + l15;
#pragma unroll
            for (int c2 = 0; c2 < 2; ++c2){
                const float* pw = whh0 + (size_t)gr*64 + c2*32 + kgrp*8;
                f16x8 v;
#pragma unroll
                for (int j = 0; j < 8; ++j) v[j] = (f16)pw[j];
                afr[q][c2] = v;
            }
            {   // chunk 2: global k 64..95 -> x rows 64..68, rest 0
                f16x8 v;
#pragma unroll
                for (int j = 0; j < 8; ++j){
                    int k = kgrp*8 + j;
                    v[j] = (k < 5) ? (f16)wih0[gr*5 + k] : (f16)0.f;
                }
                afr[q][2] = v;
            }
            afr[q][3] = (f16x8)(f16)0.f;   // unused by X
            const int gu = q*64 + ug*16 + uloc;
            bpk[q] = bih0[gu] + bhh0[gu];
        }
        cOwn = c0i[(size_t)(r0+bb)*64 + ug*16 + uloc];
    } else {
#pragma unroll
        for (int q = 0; q < 4; ++q){
            const int gr = q*64 + ug*16 + l15;
#pragma unroll
            for (int c2 = 0; c2 < 2; ++c2){
                const float* pw = wih1 + (size_t)gr*64 + c2*32 + kgrp*8;
                const float* qw = whh1 + (size_t)gr*64 + c2*32 + kgrp*8;
                f16x8 v, u2;
#pragma unroll
                for (int j = 0; j < 8; ++j){ v[j] = (f16)pw[j]; u2[j] = (f16)qw[j]; }
                afr[q][c2]   = v;
                afr[q][2+c2] = u2;
            }
            const int gu = q*64 + ug*16 + uloc;
            bpk[q] = bih1[gu] + bhh1[gu];
        }
        cOwn = c0i[(size_t)B_TOT*64 + (size_t)(r0+bb)*64 + ug*16 + uloc];
    }

    // ---------- LDS init ----------
    for (int e = tid; e < 2*16*HROW; e += NT){
        ((f16*)hbuf)[e] = (f16)0.f;
        ((f16*)ybuf)[e] = (f16)0.f;
    }
    __syncthreads();
    if (tid < ROWS*64){
        int cc = tid >> 6, u = tid & 63;
        hbuf[0][cc][u] = (f16)h0i[(size_t)(r0+cc)*64 + u];
        ybuf[1][cc][u] = (f16)h0i[(size_t)B_TOT*64 + (size_t)(r0+cc)*64 + u];
    }
    if (tid < ROWS*5){
        int cc = tid/5, i = tid - cc*5;
        hbuf[0][cc][64+i] = (f16)x[(size_t)(r0+cc)*T_TOT*5 + i];  // x[0]
    }
    for (int e = tid; e < ROWS*XT*5; e += NT){
        int r = e/(XT*5), rem = e - r*(XT*5), ts = rem/5, i = rem - ts*5;
        xt[r][ts][i] = x[((size_t)(r0+r)*T_TOT + ts)*5 + i];      // tile 0
    }
    __syncthreads();

    // ---------- 513 pipelined ticks: X = layer0 step t, Y = layer1 step t-1 ----------
#pragma unroll 1
    for (int t = 0; t <= T_TOT; ++t){
        const int p = t & 1;

        if ((t+1) < T_TOT && ((t+1) & 31) == 0){      // stage next x tile
            for (int e = tid; e < ROWS*XT*5; e += NT){
                int r = e/(XT*5), rem = e - r*(XT*5), ts = rem/5, i = rem - ts*5;
                xt[r][ts][i] = x[((size_t)(r0+r)*T_TOT + (t+1+ts))*5 + i];
            }
            __syncthreads();
        }
        if ((t+1) < T_TOT && tid < ROWS*5){           // x[t+1] -> write buffer
            int cc = tid/5, i = tid - cc*5;
            hbuf[p^1][cc][64+i] = (f16)xt[cc][(t+1)&31][i];
        }

        if (isX){ if (t < T_TOT){
            const f16* bp = &hbuf[p][l15][kgrp*8];
            f16x8 b0 = *(const f16x8*)(bp);
            f16x8 b1 = *(const f16x8*)(bp + 32);
            f16x8 b2 = *(const f16x8*)(bp + 64);
#pragma unroll
            for (int q = 0; q < 4; ++q){
                f32x4 a = {0.f,0.f,0.f,0.f};
                a = MFMA16(afr[q][0], b0, a);
                a = MFMA16(afr[q][1], b1, a);
                a = MFMA16(afr[q][2], b2, a);
                if (l15 < ROWS) *(f32x4*)&gbuf[wv][q][l15][kgrp*4] = a;
            }
            if (act){
                float ii = gbuf[wv][0][bb][uloc] + bpk[0];
                float ff = gbuf[wv][1][bb][uloc] + bpk[1];
                float gg = gbuf[wv][2][bb][uloc] + bpk[2];
                float oo = gbuf[wv][3][bb][uloc] + bpk[3];
                cOwn = sig_f(ff)*cOwn + sig_f(ii)*tanh_f(gg);
                hbuf[p^1][bb][ug*16 + uloc] = (f16)(sig_f(oo)*tanh_f(cOwn));
            }
        }} else { if (t >= 1){
            const f16* hp = &hbuf[p][l15][kgrp*8];
            f16x8 b0 = *(const f16x8*)(hp);
            f16x8 b1 = *(const f16x8*)(hp + 32);
            const f16* yp = &ybuf[p][l15][kgrp*8];
            f16x8 b2 = *(const f16x8*)(yp);
            f16x8 b3 = *(const f16x8*)(yp + 32);
#pragma unroll
            for (int q = 0; q < 4; ++q){
                f32x4 a = {0.f,0.f,0.f,0.f};
                a = MFMA16(afr[q][0], b0, a);
                a = MFMA16(afr[q][1], b1, a);
                a = MFMA16(afr[q][2], b2, a);
                a = MFMA16(afr[q][3], b3, a);
                if (l15 < ROWS) *(f32x4*)&gbuf[wv][q][l15][kgrp*4] = a;
            }
            if (act){
                float ii = gbuf[wv][0][bb][uloc] + bpk[0];
                float ff = gbuf[wv][1][bb][uloc] + bpk[1];
                float gg = gbuf[wv][2][bb][uloc] + bpk[2];
                float oo = gbuf[wv][3][bb][uloc] + bpk[3];
                cOwn = sig_f(ff)*cOwn + sig_f(ii)*tanh_f(gg);
                ybuf[p^1][bb][ug*16 + uloc] = (f16)(sig_f(oo)*tanh_f(cOwn));
            }
        }}
        __syncthreads();
    }

    // ---------- heads: final h1 = ybuf[1] (written at tick 512) ----------
    if (wv < ROWS){
        const int cc = wv, u = lane;
        float hr = (float)ybuf[1][cc][u];
        float pm = hr * wmean[u];
        float pc = hr * wcrit[u];
#pragma unroll
        for (int o = 32; o > 0; o >>= 1){
            pm += __shfl_down(pm, o);
            pc += __shfl_down(pc, o);
        }
        if (u == 0){
            float m = pm + bmean[0];
            out[r0+cc]           = 2.f*tanh_f(m);
            out[B_TOT + r0+cc]   = __logf(1.f + __expf(m));
            out[2*B_TOT + r0+cc] = pc + bcrit[0];
        }
    }
}

extern "C" void kernel_launch(void* const* d_in, const int* in_sizes, int n_in,
                              void* d_out, int out_size, void* d_ws, size_t ws_size,
                              hipStream_t stream) {
    const float* x     = (const float*)d_in[0];
    const float* h0i   = (const float*)d_in[1];
    const float* c0i   = (const float*)d_in[2];
    const float* wih0  = (const float*)d_in[3];
    const float* whh0  = (const float*)d_in[4];
    const float* bih0  = (const float*)d_in[5];
    const float* bhh0  = (const float*)d_in[6];
    const float* wih1  = (const float*)d_in[7];
    const float* whh1  = (const float*)d_in[8];
    const float* bih1  = (const float*)d_in[9];
    const float* bhh1  = (const float*)d_in[10];
    const float* wmean = (const float*)d_in[11];
    const float* bmean = (const float*)d_in[12];
    const float* wcrit = (const float*)d_in[13];
    const float* bcrit = (const float*)d_in[14];

    lstm_pipe<<<NB, NT, 0, stream>>>(x, h0i, c0i, wih0, whh0, bih0, bhh0,
                                     wih1, whh1, bih1, bhh1,
                                     wmean, bmean, wcrit, bcrit,
                                     (float*)d_out);
}

// Round 10
// 390.807 us; speedup vs baseline: 2.6002x; 1.2585x over previous
//
#include <hip/hip_runtime.h>
#include <math.h>

#define NB    256   // blocks, 4 batch rows each (fills all CUs)
#define NT    512   // 8 waves: 0-3 layer0 (X), 4-7 layer1 (Y)
#define ROWS  4
#define B_TOT 1024
#define T_TOT 512
#define HROW  104   // f16 per h-row (208 B stride; 16B-aligned; 2-way banks max)
#define XT    32

typedef _Float16 f16;
typedef _Float16 f16x8 __attribute__((ext_vector_type(8)));
typedef float    f32x4 __attribute__((ext_vector_type(4)));

__device__ __forceinline__ float rcp_f(float v){ return __builtin_amdgcn_rcpf(v); }
__device__ __forceinline__ float sig_f(float x){ return rcp_f(1.0f + __expf(-x)); }
__device__ __forceinline__ float tanh_f(float x){ return 1.0f - 2.0f*rcp_f(__expf(2.0f*x) + 1.0f); }

#define MFMA16(a,b,c) __builtin_amdgcn_mfma_f32_16x16x32_f16((a),(b),(c),0,0,0)

__global__ __launch_bounds__(NT, 2) void lstm_tr(
    const float* __restrict__ x,
    const float* __restrict__ h0i, const float* __restrict__ c0i,
    const float* __restrict__ wih0, const float* __restrict__ whh0,
    const float* __restrict__ bih0, const float* __restrict__ bhh0,
    const float* __restrict__ wih1, const float* __restrict__ whh1,
    const float* __restrict__ bih1, const float* __restrict__ bhh1,
    const float* __restrict__ wmean, const float* __restrict__ bmean,
    const float* __restrict__ wcrit, const float* __restrict__ bcrit,
    float* __restrict__ out)
{
    const int tid  = threadIdx.x;
    const int lane = tid & 63;
    const int wv   = tid >> 6;
    const bool isX = (wv < 4);        // layer-0 waves
    const int ug   = wv & 3;          // unit-group: units [16ug, 16ug+16)
    const int l15  = lane & 15;       // A row (batch) / B col (gate) / D col
    const int kgrp = lane >> 4;       // k-group; D rows = kgrp*4+r; owned batch row
    const int r0   = blockIdx.x * ROWS;
    const int un   = ug*16 + l15;     // owned unit (this lane's gate column)

    // rows = batch (0-3 real, 4-15 zero pad). cols: 0-63 h, 64-68 x (hbuf only), 69+ 0
    __shared__ __align__(16) f16 hbuf[2][16][HROW];
    __shared__ __align__(16) f16 ybuf[2][16][HROW];
    __shared__ float xt[ROWS][XT][5];

    // ---- B-fragments (weights, constant): B[k][n] = W[gate n][k] ----
    f16x8 bfr[4][4];   // [gate q][k-chunk]
    float bq[4];       // bias per gate for this lane's unit column
    float cOwn;        // owned cell state: (batch row kgrp, unit un)

    if (isX){
#pragma unroll
        for (int q = 0; q < 4; ++q){
            const int gr = q*64 + un;
#pragma unroll
            for (int c2 = 0; c2 < 2; ++c2){
                const float* pw = whh0 + (size_t)gr*64 + c2*32 + kgrp*8;
                f16x8 v;
#pragma unroll
                for (int j = 0; j < 8; ++j) v[j] = (f16)pw[j];
                bfr[q][c2] = v;
            }
            {   // chunk 2: k = 64..95 -> x-weight rows 64..68, rest 0
                f16x8 v;
#pragma unroll
                for (int j = 0; j < 8; ++j){
                    int k = kgrp*8 + j;
                    v[j] = (k < 5) ? (f16)wih0[gr*5 + k] : (f16)0.f;
                }
                bfr[q][2] = v;
            }
            bfr[q][3] = (f16x8)(f16)0.f;    // unused by X
            bq[q] = bih0[gr] + bhh0[gr];
        }
        cOwn = c0i[(size_t)(r0+kgrp)*64 + un];
    } else {
#pragma unroll
        for (int q = 0; q < 4; ++q){
            const int gr = q*64 + un;
#pragma unroll
            for (int c2 = 0; c2 < 2; ++c2){
                const float* pw = wih1 + (size_t)gr*64 + c2*32 + kgrp*8;
                const float* qw = whh1 + (size_t)gr*64 + c2*32 + kgrp*8;
                f16x8 v, u2;
#pragma unroll
                for (int j = 0; j < 8; ++j){ v[j] = (f16)pw[j]; u2[j] = (f16)qw[j]; }
                bfr[q][c2]   = v;
                bfr[q][2+c2] = u2;
            }
            bq[q] = bih1[gr] + bhh1[gr];
        }
        cOwn = c0i[(size_t)B_TOT*64 + (size_t)(r0+kgrp)*64 + un];
    }

    // ---- LDS init: zero everything (pad rows/cols), then real data ----
    for (int e = tid; e < 2*16*HROW; e += NT){
        ((f16*)hbuf)[e] = (f16)0.f;
        ((f16*)ybuf)[e] = (f16)0.f;
    }
    __syncthreads();
    if (tid < ROWS*64){
        int cc = tid >> 6, u = tid & 63;
        hbuf[0][cc][u] = (f16)h0i[(size_t)(r0+cc)*64 + u];
        ybuf[1][cc][u] = (f16)h0i[(size_t)B_TOT*64 + (size_t)(r0+cc)*64 + u];
    }
    if (tid < ROWS*5){
        int cc = tid/5, i = tid - cc*5;
        hbuf[0][cc][64+i] = (f16)x[(size_t)(r0+cc)*T_TOT*5 + i];  // x[0]
    }
    for (int e = tid; e < ROWS*XT*5; e += NT){
        int r = e/(XT*5), rem = e - r*(XT*5), ts = rem/5, i = rem - ts*5;
        xt[r][ts][i] = x[((size_t)(r0+r)*T_TOT + ts)*5 + i];      // tile 0
    }
    __syncthreads();

    // ---- 513 pipelined ticks: X = layer0 step t, Y = layer1 step t-1 ----
#pragma unroll 1
    for (int t = 0; t <= T_TOT; ++t){
        const int p = t & 1;

        if ((t+1) < T_TOT && ((t+1) & 31) == 0){      // stage next x tile
            for (int e = tid; e < ROWS*XT*5; e += NT){
                int r = e/(XT*5), rem = e - r*(XT*5), ts = rem/5, i = rem - ts*5;
                xt[r][ts][i] = x[((size_t)(r0+r)*T_TOT + (t+1+ts))*5 + i];
            }
            __syncthreads();
        }
        if ((t+1) < T_TOT && tid < ROWS*5){           // x[t+1] -> write buffer
            int cc = tid/5, i = tid - cc*5;
            hbuf[p^1][cc][64+i] = (f16)xt[cc][(t+1)&31][i];
        }

        if (isX){ if (t < T_TOT){
            // A = h0[t-1] (+ x[t] cols): lane reads batch row l15, k-chunk kgrp
            const f16* ap = &hbuf[p][l15][kgrp*8];
            f16x8 a0 = *(const f16x8*)(ap);            // k 0..31
            f16x8 a1 = *(const f16x8*)(ap + 32);       // k 32..63
            f16x8 a2 = *(const f16x8*)(ap + 64);       // k 64..95 (x|0)
            f32x4 ac[4];
#pragma unroll
            for (int q = 0; q < 4; ++q){
                f32x4 a = {bq[q], bq[q], bq[q], bq[q]};   // bias: same for all batch rows
                a = MFMA16(a0, bfr[q][0], a);
                a = MFMA16(a1, bfr[q][1], a);
                a = MFMA16(a2, bfr[q][2], a);
                ac[q] = a;
            }
            // redistribute: lane (l15,kgrp) takes D[row kgrp][col l15] from lane l15
            float g[4];
#pragma unroll
            for (int q = 0; q < 4; ++q){
                float t0 = __shfl(ac[q][0], l15);
                float t1 = __shfl(ac[q][1], l15);
                float t2 = __shfl(ac[q][2], l15);
                float t3 = __shfl(ac[q][3], l15);
                g[q] = (kgrp==0) ? t0 : (kgrp==1) ? t1 : (kgrp==2) ? t2 : t3;
            }
            cOwn = sig_f(g[1])*cOwn + sig_f(g[0])*tanh_f(g[2]);
            float hn = sig_f(g[3])*tanh_f(cOwn);
            hbuf[p^1][kgrp][un] = (f16)hn;
        }} else { if (t >= 1){
            const f16* hp = &hbuf[p][l15][kgrp*8];
            f16x8 a0 = *(const f16x8*)(hp);            // h0_new k 0..31
            f16x8 a1 = *(const f16x8*)(hp + 32);       // h0_new k 32..63
            const f16* yp = &ybuf[p][l15][kgrp*8];
            f16x8 a2 = *(const f16x8*)(yp);            // h1_old k 0..31
            f16x8 a3 = *(const f16x8*)(yp + 32);       // h1_old k 32..63
            f32x4 ac[4];
#pragma unroll
            for (int q = 0; q < 4; ++q){
                f32x4 a = {bq[q], bq[q], bq[q], bq[q]};
                a = MFMA16(a0, bfr[q][0], a);
                a = MFMA16(a1, bfr[q][1], a);
                a = MFMA16(a2, bfr[q][2], a);
                a = MFMA16(a3, bfr[q][3], a);
                ac[q] = a;
            }
            float g[4];
#pragma unroll
            for (int q = 0; q < 4; ++q){
                float t0 = __shfl(ac[q][0], l15);
                float t1 = __shfl(ac[q][1], l15);
                float t2 = __shfl(ac[q][2], l15);
                float t3 = __shfl(ac[q][3], l15);
                g[q] = (kgrp==0) ? t0 : (kgrp==1) ? t1 : (kgrp==2) ? t2 : t3;
            }
            cOwn = sig_f(g[1])*cOwn + sig_f(g[0])*tanh_f(g[2]);
            float hn = sig_f(g[3])*tanh_f(cOwn);
            ybuf[p^1][kgrp][un] = (f16)hn;
        }}
        __syncthreads();
    }

    // ---- heads: final h1 = ybuf[1] (tick 512, p=0, wrote p^1=1) ----
    if (wv < ROWS){
        const int cc = wv, u = lane;
        float hr = (float)ybuf[1][cc][u];
        float pm = hr * wmean[u];
        float pc = hr * wcrit[u];
#pragma unroll
        for (int o = 32; o > 0; o >>= 1){
            pm += __shfl_down(pm, o);
            pc += __shfl_down(pc, o);
        }
        if (u == 0){
            float m = pm + bmean[0];
            out[r0+cc]           = 2.f*tanh_f(m);
            out[B_TOT + r0+cc]   = __logf(1.f + __expf(m));
            out[2*B_TOT + r0+cc] = pc + bcrit[0];
        }
    }
}

extern "C" void kernel_launch(void* const* d_in, const int* in_sizes, int n_in,
                              void* d_out, int out_size, void* d_ws, size_t ws_size,
                              hipStream_t stream) {
    const float* x     = (const float*)d_in[0];
    const float* h0i   = (const float*)d_in[1];
    const float* c0i   = (const float*)d_in[2];
    const float* wih0  = (const float*)d_in[3];
    const float* whh0  = (const float*)d_in[4];
    const float* bih0  = (const float*)d_in[5];
    const float* bhh0  = (const float*)d_in[6];
    const float* wih1  = (const float*)d_in[7];
    const float* whh1  = (const float*)d_in[8];
    const float* bih1  = (const float*)d_in[9];
    const float* bhh1  = (const float*)d_in[10];
    const float* wmean = (const float*)d_in[11];
    const float* bmean = (const float*)d_in[12];
    const float* wcrit = (const float*)d_in[13];
    const float* bcrit = (const float*)d_in[14];

    lstm_tr<<<NB, NT, 0, stream>>>(x, h0i, c0i, wih0, whh0, bih0, bhh0,
                                   wih1, whh1, bih1, bhh1,
                                   wmean, bmean, wcrit, bcrit,
                                   (float*)d_out);
}